// Round 4
// baseline (466.272 us; speedup 1.0000x reference)
//
#include <hip/hip_runtime.h>
#include <math.h>

#define N_NODES 661
#define N_GRAPH 128
#define DEG 8
#define EPG (N_NODES*DEG)          // 5288 edges per graph per matrix
#define NTOT (N_NODES*N_GRAPH)     // 84608 nodes
#define FDIM 64
#define NF ((size_t)NTOT*FDIM)     // elements per [n,64] array
#define OSTR 672                   // padded CSR offsets stride
#define PSTR 7296                  // padded pairs stride (>= 5288 + 3*661 = 7271)
#define NTILE 11
#define TROWS 61                   // 11*61 = 671 >= 661
#define NCOPY 1056                 // ef-pack blocks appended to csr_build
#define PCAP 1024                  // staged pairs per matrix per tile (mean ~575)
#define FCH 4                      // chunks (16 nodes) per final_fused block

using short8  = __attribute__((ext_vector_type(8))) short;
using float4v = __attribute__((ext_vector_type(4))) float;

__device__ __forceinline__ unsigned short f2bf(float x) {
    unsigned int u = __float_as_uint(x);
    unsigned int r = u + 0x7FFFu + ((u >> 16) & 1u);
    return (unsigned short)(r >> 16);
}
__device__ __forceinline__ float bf2f(unsigned short h) {
    return __uint_as_float(((unsigned int)h) << 16);
}
// pack float into (bf16_hi << 16) | bf16_lo residual
__device__ __forceinline__ unsigned pack_bf(float x) {
    unsigned short h = f2bf(x);
    unsigned short l = f2bf(x - bf2f(h));
    return ((unsigned)h << 16) | (unsigned)l;
}

// async global->LDS, 16B per lane: LDS dest = uniform base + lane*16,
// global src = per-lane address (must be base + lane*16 to match).
__device__ __forceinline__ void gl2lds16(const unsigned* g, unsigned* l) {
    __builtin_amdgcn_global_load_lds(
        (const __attribute__((address_space(1))) unsigned*)g,
        (__attribute__((address_space(3))) unsigned*)l, 16, 0, 0);
}

// ---------------------------------------------------------------------------
// Kernel 1 (fused): blocks 0..511 -> per-(graph,matrix) LDS counting sort ->
// PADDED CSR (rows padded to multiple of 4 slots with val=0 pairs -> the
// gather inner loop needs no predicates/clamps). Pairs scattered DIRECTLY to
// global. blocks 512..591 -> wtrans (bf16 hi/lo W fragments, MFMA B-layout).
// blocks 592.. -> pack e/f into efh=(bf16e_hi<<16)|bf16f_hi and
// eflo=(bf16e_lo<<16)|bf16f_lo.
// ---------------------------------------------------------------------------
__global__ __launch_bounds__(256) void csr_build(
    const int* __restrict__ rG, const int* __restrict__ cG, const float* __restrict__ vG,
    const int* __restrict__ rB, const int* __restrict__ cB, const float* __restrict__ vB,
    const int* __restrict__ r1, const int* __restrict__ c1, const float* __restrict__ v1,
    const int* __restrict__ r2, const int* __restrict__ c2, const float* __restrict__ v2,
    const float* __restrict__ W1, const float* __restrict__ W2,
    const float* __restrict__ e, const float* __restrict__ f,
    unsigned short* __restrict__ Wb1h, unsigned short* __restrict__ Wb1l,
    unsigned short* __restrict__ Wb2h, unsigned short* __restrict__ Wb2l,
    int* __restrict__ offs_out, int2* __restrict__ pairs_out,
    unsigned* __restrict__ efh, unsigned* __restrict__ eflo)
{
    int bid = blockIdx.x;
    int tid = threadIdx.x;

    if (bid >= 592) {                     // ---- ef bf16 hi/lo pair pack ----
        const int nf4 = (int)(NF/4);
        int i0 = (bid - 592)*256 + tid;
        const int stride = NCOPY*256;
        const float4v* e4 = (const float4v*)e;
        const float4v* f4 = (const float4v*)f;
        uint4* oh = (uint4*)efh;
        uint4* ol = (uint4*)eflo;
        for (int i = i0; i < nf4; i += stride) {
            float4v ev = e4[i];
            float4v fv = f4[i];
            uint4 uh, ul;
            unsigned short h, l;
            #define PK(idx, FLD) \
                h = f2bf(ev[idx]); l = f2bf(ev[idx] - bf2f(h)); \
                uh.FLD = ((unsigned)h << 16); ul.FLD = ((unsigned)l << 16); \
                h = f2bf(fv[idx]); l = f2bf(fv[idx] - bf2f(h)); \
                uh.FLD |= (unsigned)h; ul.FLD |= (unsigned)l;
            PK(0, x) PK(1, y) PK(2, z) PK(3, w)
            #undef PK
            oh[i] = uh;
            ol[i] = ul;
        }
        return;
    }

    if (bid >= 512) {                     // ---- wtrans part ----
        int i = (bid - 512)*256 + tid;    // 0..20479
        int j    = i & 7;
        int lane = (i >> 3) & 63;
        int ot   = (i >> 9) & 3;
        int ks   = i >> 11;
        int k = ks*32 + (lane >> 4)*8 + j;
        int o = ot*16 + (lane & 15);
        float w1 = W1[o*320 + k];
        float w2 = W2[o*320 + k];
        unsigned short h1 = f2bf(w1); Wb1h[i] = h1; Wb1l[i] = f2bf(w1 - bf2f(h1));
        unsigned short h2 = f2bf(w2); Wb2h[i] = h2; Wb2l[i] = f2bf(w2 - bf2f(h2));
        return;
    }

    __shared__ int   scount[N_NODES];
    __shared__ int   soffs[N_NODES+1];
    __shared__ int   scursor[N_NODES];
    __shared__ int   sscan[256];

    int g = bid & 127;
    int m = bid >> 7;
    const int*   rows = (m==0)?rG:(m==1)?rB:(m==2)?r1:r2;
    const int*   cols = (m==0)?cG:(m==1)?cB:(m==2)?c1:c2;
    const float* vals = (m==0)?vG:(m==1)?vB:(m==2)?v1:v2;

    int ebase = g*EPG;
    int gbase = g*N_NODES;
    int seg = m*N_GRAPH + g;
    int2* po = pairs_out + (size_t)seg*PSTR;

    for (int i = tid; i < N_NODES; i += 256) scount[i] = 0;
    __syncthreads();
    for (int i = tid; i < EPG; i += 256)
        atomicAdd(&scount[rows[ebase+i] - gbase], 1);
    __syncthreads();

    int c0 = tid*3;
    int ps = 0;
    #pragma unroll
    for (int j = 0; j < 3; ++j) {
        int i = c0+j;
        if (i < N_NODES) ps += (scount[i] + 3) & ~3;   // padded counts
    }
    sscan[tid] = ps;
    __syncthreads();
    #pragma unroll
    for (int d = 1; d < 256; d <<= 1) {
        int v = (tid >= d) ? sscan[tid-d] : 0;
        __syncthreads();
        sscan[tid] += v;
        __syncthreads();
    }
    int run = sscan[tid] - ps;   // exclusive prefix (padded)
    #pragma unroll
    for (int j = 0; j < 3; ++j) {
        int i = c0+j;
        if (i < N_NODES) {
            soffs[i] = run; scursor[i] = run;
            run += (scount[i] + 3) & ~3;
        }
    }
    if (tid == 255) soffs[N_NODES] = sscan[255];
    __syncthreads();

    // placement: scatter real pairs straight to global
    for (int i = tid; i < EPG; i += 256) {
        int r = rows[ebase+i] - gbase;
        int pos = atomicAdd(&scursor[r], 1);
        po[pos] = make_int2(cols[ebase+i], __float_as_int(vals[ebase+i]));
    }
    // pad slots (val=0, valid col) — disjoint from real slots, no barrier needed
    for (int i = tid; i < N_NODES; i += 256) {
        int d = scount[i];
        int s = soffs[i] + d, epad = soffs[i] + ((d + 3) & ~3);
        for (int k = s; k < epad; ++k) po[k] = make_int2(gbase, 0);
    }
    for (int i = tid; i <= N_NODES; i += 256)
        offs_out[(size_t)seg*OSTR + i] = soffs[i];
}

// ---------------------------------------------------------------------------
__device__ __forceinline__ void node_math1(
    float ev, float fv, float gd, float bd, float pd, float qd,
    float eGv, float fGv, float eBv, float fBv,
    float& e3v, float& nev, float& f3v, float& nfv)
{
    float invb = 1.0f/(ev*ev + fv*fv + 0.1f);
    float alpha = (pd*ev + qd*fv)*invb - eGv - fBv;
    float beta  = (qd*ev - pd*fv)*invb + fGv + eBv;
    float invg = 1.0f/(gd*gd + bd*bd);
    e3v = (alpha*gd + beta*bd)*invg;
    f3v = (beta*gd - alpha*bd)*invg;
    float bb1 = eGv - fBv, bb2 = fGv + eBv;
    float vv = ev*ev + fv*fv;
    float P_ = pd - vv*gd, Q_ = qd + vv*bd;
    nev = (P_*bb1 + Q_*bb2)*invg;
    nfv = (P_*bb2 - Q_*bb1)*invg;
}

// 4-slot chunk: pairs from PGET (LDS or global), one efh gather per slot,
// no predicates (CSR rows padded with val=0 at build time).
#define DOT4(PGET, s, t, accE, accF)                                          \
    for (int k = (s); k < (t); k += 4) {                                      \
        int2 p0 = PGET(k);   int2 p1 = PGET(k+1);                             \
        int2 p2 = PGET(k+2); int2 p3 = PGET(k+3);                             \
        unsigned u0 = efh[((unsigned)p0.x << 6) + lane];                      \
        unsigned u1 = efh[((unsigned)p1.x << 6) + lane];                      \
        unsigned u2 = efh[((unsigned)p2.x << 6) + lane];                      \
        unsigned u3 = efh[((unsigned)p3.x << 6) + lane];                      \
        accE = fmaf(__int_as_float(p0.y), __uint_as_float(u0 & 0xFFFF0000u), accE); \
        accF = fmaf(__int_as_float(p0.y), __uint_as_float(u0 << 16), accF);   \
        accE = fmaf(__int_as_float(p1.y), __uint_as_float(u1 & 0xFFFF0000u), accE); \
        accF = fmaf(__int_as_float(p1.y), __uint_as_float(u1 << 16), accF);   \
        accE = fmaf(__int_as_float(p2.y), __uint_as_float(u2 & 0xFFFF0000u), accE); \
        accF = fmaf(__int_as_float(p2.y), __uint_as_float(u2 << 16), accF);   \
        accE = fmaf(__int_as_float(p3.y), __uint_as_float(u3 & 0xFFFF0000u), accE); \
        accF = fmaf(__int_as_float(p3.y), __uint_as_float(u3 << 16), accF);   \
    }

// ---------------------------------------------------------------------------
// Kernel 2: gather SpMM v7 = v6 with sane launch bounds (no forced spills).
// Tile's padded-CSR pairs + offsets staged in LDS; inner loop predicate-free.
// arrs: [0]=e3 [1]=ne [2]=e1 [3]=e2 [4]=f3 [5]=nf [6]=f1 [7]=f2
// Grid: 2816 = 8 XCD * 16 graphs * 22 (11 tiles x 2 sets).
// ---------------------------------------------------------------------------
__global__ __launch_bounds__(256, 4) void gather_all(
    const float* __restrict__ e, const float* __restrict__ f,
    const unsigned* __restrict__ efh,
    const float* __restrict__ Gd, const float* __restrict__ Bd,
    const float* __restrict__ Pd, const float* __restrict__ Qd,
    const float* __restrict__ w_ae, const float* __restrict__ w_af,
    const int* __restrict__ offs, const int2* __restrict__ pairs,
    unsigned* __restrict__ arrs, float* __restrict__ partials)
{
    __shared__ int soA[TROWS+1], soB[TROWS+1];
    __shared__ __align__(16) int2 spA[PCAP], spB[PCAP];

    int tid = threadIdx.x, lane = tid & 63, wv = tid >> 6;
    int bid = blockIdx.x;
    int xcd = bid & 7, loc = bid >> 3;          // loc 0..351
    int g    = xcd*16 + loc/22;
    int sub  = loc % 22;
    int set  = (sub < NTILE) ? 0 : 1;
    int tile = sub - set*NTILE;
    int r0   = tile*TROWS;
    int rlim = min(TROWS, N_NODES - r0);
    int mA = set ? 2 : 0, mB = set ? 3 : 1;

    const int*  poA = offs + (size_t)(mA*N_GRAPH + g)*OSTR + r0;
    const int*  poB = offs + (size_t)(mB*N_GRAPH + g)*OSTR + r0;
    const int2* ppA = pairs + (size_t)(mA*N_GRAPH + g)*PSTR;
    const int2* ppB = pairs + (size_t)(mB*N_GRAPH + g)*PSTR;

    for (int i = tid; i <= rlim; i += 256) { soA[i] = poA[i]; soB[i] = poB[i]; }
    __syncthreads();
    int offA0 = __builtin_amdgcn_readfirstlane(soA[0]);
    int offB0 = __builtin_amdgcn_readfirstlane(soB[0]);
    int cntA  = __builtin_amdgcn_readfirstlane(soA[rlim]) - offA0;
    int cntB  = __builtin_amdgcn_readfirstlane(soB[rlim]) - offB0;
    {
        int limA = min(cntA, PCAP), limB = min(cntB, PCAP);
        for (int i = tid; i < limA; i += 256) spA[i] = ppA[offA0 + i];
        for (int i = tid; i < limB; i += 256) spB[i] = ppB[offB0 + i];
    }
    __syncthreads();

    float wa = w_ae[lane], wf = w_af[lane];
    float pa0 = 0.f, pa1 = 0.f, pa2 = 0.f, pa3 = 0.f;

    #define PGET_LA(k) spA[k]
    #define PGET_LB(k) spB[k]
    #define PGET_GA(k) ppA[offA0 + (k)]
    #define PGET_GB(k) ppB[offB0 + (k)]

    for (int lr = wv; lr < rlim; lr += 4) {
        int r = r0 + lr;
        int sA = __builtin_amdgcn_readfirstlane(soA[lr])   - offA0;
        int tA = __builtin_amdgcn_readfirstlane(soA[lr+1]) - offA0;
        int sB = __builtin_amdgcn_readfirstlane(soB[lr])   - offB0;
        int tB = __builtin_amdgcn_readfirstlane(soB[lr+1]) - offB0;

        float aE = 0.f, aF = 0.f, bE = 0.f, bF = 0.f;

        if (tA <= PCAP) { DOT4(PGET_LA, sA, tA, aE, aF) }
        else            { DOT4(PGET_GA, sA, tA, aE, aF) }
        if (tB <= PCAP) { DOT4(PGET_LB, sB, tB, bE, bF) }
        else            { DOT4(PGET_GB, sB, tB, bE, bF) }

        int node = g*N_NODES + r;
        size_t idx = (size_t)node*FDIM + lane;
        if (set == 0) {
            float ev = e[idx], fv = f[idx];
            float gd = Gd[node], bd = Bd[node], pd = Pd[node], qd = Qd[node];
            float e3v, nev, f3v, nfv;
            node_math1(ev, fv, gd, bd, pd, qd, aE, aF, bE, bF, e3v, nev, f3v, nfv);
            __builtin_nontemporal_store(pack_bf(e3v), &arrs[0*NF + idx]);
            __builtin_nontemporal_store(pack_bf(nev), &arrs[1*NF + idx]);
            __builtin_nontemporal_store(pack_bf(f3v), &arrs[4*NF + idx]);
            __builtin_nontemporal_store(pack_bf(nfv), &arrs[5*NF + idx]);
            pa0 += e3v*wa; pa1 += nev*wa; pa2 += f3v*wf; pa3 += nfv*wf;
        } else {
            __builtin_nontemporal_store(pack_bf(aE), &arrs[2*NF + idx]);   // e1
            __builtin_nontemporal_store(pack_bf(bE), &arrs[3*NF + idx]);   // e2
            __builtin_nontemporal_store(pack_bf(aF), &arrs[6*NF + idx]);   // f1
            __builtin_nontemporal_store(pack_bf(bF), &arrs[7*NF + idx]);   // f2
            pa0 += aE*wa; pa1 += bE*wa; pa2 += aF*wf; pa3 += bF*wf;
        }
    }

    __shared__ float sred[4];
    if (tid < 4) sred[tid] = 0.f;
    __syncthreads();
    #pragma unroll
    for (int off = 32; off > 0; off >>= 1) {
        pa0 += __shfl_down(pa0, off); pa1 += __shfl_down(pa1, off);
        pa2 += __shfl_down(pa2, off); pa3 += __shfl_down(pa3, off);
    }
    if (lane == 0) {
        atomicAdd(&sred[0], pa0); atomicAdd(&sred[1], pa1);
        atomicAdd(&sred[2], pa2); atomicAdd(&sred[3], pa3);
    }
    __syncthreads();
    if (tid == 0) {
        float* pt = partials + ((size_t)g*NTILE + tile)*8;
        if (set == 0) { pt[0] = sred[0]; pt[1] = sred[1]; pt[4] = sred[2]; pt[5] = sred[3]; }
        else          { pt[2] = sred[0]; pt[3] = sred[1]; pt[6] = sred[2]; pt[7] = sred[3]; }
    }
}

// ---------------------------------------------------------------------------
// Kernel 3: finalize attention -> NORMALIZED weights att[g][0..3]=e, [4..7]=f
// ---------------------------------------------------------------------------
__global__ void attn_final(const float* __restrict__ partials,
                           const float* __restrict__ b_ae, const float* __restrict__ b_af,
                           float* __restrict__ att)
{
    int g = threadIdx.x;
    if (g >= N_GRAPH) return;
    float s[8];
    #pragma unroll
    for (int j = 0; j < 8; ++j) {
        float t = 0.f;
        for (int q = 0; q < NTILE; ++q) t += partials[((size_t)g*NTILE + q)*8 + j];
        s[j] = t;
    }
    float ae[4], af[4], se = 1e-4f, sf = 1e-4f;
    float bae = b_ae[0], baf = b_af[0];
    #pragma unroll
    for (int j = 0; j < 4; ++j) {
        float x = s[j]*(1.0f/N_NODES) + bae;
        ae[j] = 1.0f/(1.0f + expf(-x)); se += ae[j];
        float y = s[4+j]*(1.0f/N_NODES) + baf;
        af[j] = 1.0f/(1.0f + expf(-y)); sf += af[j];
    }
    #pragma unroll
    for (int j = 0; j < 4; ++j) {
        att[g*8 + j]     = ae[j]/se;
        att[g*8 + 4 + j] = af[j]/sf;
    }
}

// ---------------------------------------------------------------------------
// Kernel 4: MFMA epilogue v3 — async LDS pipeline. Per 16-node chunk: 8 arrs
// slabs (4KB each) staged via global_load_lds_dwordx4 (32KB LDS), e/f segs
// prefetched to regs; ds_read_b128 fragments -> MFMA; 3 blocks/CU overlap
// staging with compute across blocks. 4 chunks per block.
// ---------------------------------------------------------------------------
__global__ __launch_bounds__(256, 3) void final_fused(
    const unsigned* __restrict__ efh, const unsigned* __restrict__ eflo,
    const unsigned* __restrict__ arrs,
    const float* __restrict__ att,
    const unsigned short* __restrict__ Wb1h, const unsigned short* __restrict__ Wb1l,
    const unsigned short* __restrict__ Wb2h, const unsigned short* __restrict__ Wb2l,
    const float* __restrict__ bv1, const float* __restrict__ bv2,
    float* __restrict__ out)
{
    __shared__ __align__(16) unsigned sbuf[8][1024];   // 32 KB

    int tid = threadIdx.x, lane = tid & 63, wv = tid >> 6;
    int m16 = lane & 15, quad = lane >> 4;
    int o = wv*16 + m16;
    float be = bv1[o], bf = bv2[o];

    for (int kc = 0; kc < FCH; ++kc) {
        int c = blockIdx.x*FCH + kc;

        // ---- stage 8 arrs slabs into LDS (8 async 1KB units per wave) ----
        {
            const unsigned* cb = arrs + (size_t)c*1024 + (unsigned)lane*4;
            #pragma unroll
            for (int u = 0; u < 8; ++u) {
                int uu = u*4 + wv;              // 0..31
                int a = uu >> 2, q = uu & 3;
                gl2lds16(cb + (size_t)a*NF + q*256, &sbuf[a][q*256]);
            }
        }
        // ---- e/f seg prefetch to regs (8x uint4) ----
        unsigned ebase = (unsigned)c*1024 + (unsigned)m16*64 + (unsigned)quad*8;
        uint4 hh0 = *(const uint4*)(efh + ebase);
        uint4 hh1 = *(const uint4*)(efh + ebase + 4);
        uint4 hh2 = *(const uint4*)(efh + ebase + 32);
        uint4 hh3 = *(const uint4*)(efh + ebase + 36);
        uint4 ll0 = *(const uint4*)(eflo + ebase);
        uint4 ll1 = *(const uint4*)(eflo + ebase + 4);
        uint4 ll2 = *(const uint4*)(eflo + ebase + 32);
        uint4 ll3 = *(const uint4*)(eflo + ebase + 36);

        __syncthreads();   // compiler drains vmcnt before barrier -> LDS valid

        float4v acce[5], accf[5];
        #pragma unroll
        for (int s = 0; s < 5; ++s) {
            acce[s] = (float4v){0.f,0.f,0.f,0.f};
            accf[s] = (float4v){0.f,0.f,0.f,0.f};
        }

        #pragma unroll
        for (int seg = 0; seg < 5; ++seg) {
            #pragma unroll
            for (int ks2 = 0; ks2 < 2; ++ks2) {
                int ks = seg*2 + ks2;
                short8 ah, al, ch, cl;
                if (seg < 4) {
                    int idx = m16*64 + ks2*32 + quad*8;
                    uint4 ea = *(const uint4*)&sbuf[seg][idx];
                    uint4 eb = *(const uint4*)&sbuf[seg][idx+4];
                    uint4 fa = *(const uint4*)&sbuf[seg+4][idx];
                    uint4 fb = *(const uint4*)&sbuf[seg+4][idx+4];
                    unsigned ue[8] = {ea.x,ea.y,ea.z,ea.w,eb.x,eb.y,eb.z,eb.w};
                    unsigned uf[8] = {fa.x,fa.y,fa.z,fa.w,fb.x,fb.y,fb.z,fb.w};
                    #pragma unroll
                    for (int j = 0; j < 8; ++j) {
                        ah[j] = (short)(ue[j] >> 16);
                        al[j] = (short)(ue[j] & 0xFFFFu);
                        ch[j] = (short)(uf[j] >> 16);
                        cl[j] = (short)(uf[j] & 0xFFFFu);
                    }
                } else {
                    uint4 ha = ks2 ? hh2 : hh0, hb = ks2 ? hh3 : hh1;
                    uint4 la = ks2 ? ll2 : ll0, lb = ks2 ? ll3 : ll1;
                    unsigned uh[8] = {ha.x,ha.y,ha.z,ha.w,hb.x,hb.y,hb.z,hb.w};
                    unsigned ul[8] = {la.x,la.y,la.z,la.w,lb.x,lb.y,lb.z,lb.w};
                    #pragma unroll
                    for (int j = 0; j < 8; ++j) {
                        ah[j] = (short)(uh[j] >> 16);        // e hi
                        al[j] = (short)(ul[j] >> 16);        // e lo
                        ch[j] = (short)(uh[j] & 0xFFFFu);    // f hi
                        cl[j] = (short)(ul[j] & 0xFFFFu);    // f lo
                    }
                }
                size_t boff = (size_t)((ks*4 + wv)*64 + lane)*8;
                short8 bh1 = *(const short8*)(Wb1h + boff);
                short8 bl1 = *(const short8*)(Wb1l + boff);
                short8 bh2 = *(const short8*)(Wb2h + boff);
                short8 bl2 = *(const short8*)(Wb2l + boff);
                acce[seg] = __builtin_amdgcn_mfma_f32_16x16x32_bf16(ah, bh1, acce[seg], 0, 0, 0);
                acce[seg] = __builtin_amdgcn_mfma_f32_16x16x32_bf16(al, bh1, acce[seg], 0, 0, 0);
                acce[seg] = __builtin_amdgcn_mfma_f32_16x16x32_bf16(ah, bl1, acce[seg], 0, 0, 0);
                accf[seg] = __builtin_amdgcn_mfma_f32_16x16x32_bf16(ch, bh2, accf[seg], 0, 0, 0);
                accf[seg] = __builtin_amdgcn_mfma_f32_16x16x32_bf16(cl, bh2, accf[seg], 0, 0, 0);
                accf[seg] = __builtin_amdgcn_mfma_f32_16x16x32_bf16(ch, bl2, accf[seg], 0, 0, 0);
            }
        }

        // ---- epilogue: normalized att (uniform scalar loads), tanh, store ----
        int g0 = (c*16)/N_NODES;
        int nb = (g0+1)*N_NODES;
        int g1 = min(g0+1, N_GRAPH-1);
        float wE0[4], wF0[4], wE1[4], wF1[4];
        #pragma unroll
        for (int b = 0; b < 4; ++b) {
            wE0[b] = att[g0*8 + b];  wF0[b] = att[g0*8 + 4 + b];
            wE1[b] = att[g1*8 + b];  wF1[b] = att[g1*8 + 4 + b];
        }
        #pragma unroll
        for (int reg = 0; reg < 4; ++reg) {
            int node = c*16 + quad*4 + reg;
            bool hi = node >= nb;
            float se2 = acce[4][reg];
            float sf2 = accf[4][reg];
            #pragma unroll
            for (int b = 0; b < 4; ++b) {
                se2 = fmaf(hi ? wE1[b] : wE0[b], acce[b][reg], se2);
                sf2 = fmaf(hi ? wF1[b] : wF0[b], accf[b][reg], sf2);
            }
            __builtin_nontemporal_store(tanhf(se2 + be), &out[(size_t)node*FDIM + o]);
            __builtin_nontemporal_store(tanhf(sf2 + bf), &out[NF + (size_t)node*FDIM + o]);
        }
        __syncthreads();   // protect sbuf before next chunk's staging
    }
}

// ---------------------------------------------------------------------------
extern "C" void kernel_launch(void* const* d_in, const int* in_sizes, int n_in,
                              void* d_out, int out_size, void* d_ws, size_t ws_size,
                              hipStream_t stream) {
    (void)in_sizes; (void)n_in; (void)out_size; (void)ws_size;
    const float* e     = (const float*)d_in[0];
    const float* f     = (const float*)d_in[1];
    const int*   rowsG = (const int*)d_in[2];
    const int*   colsG = (const int*)d_in[3];
    const float* valsG = (const float*)d_in[4];
    const int*   rowsB = (const int*)d_in[5];
    const int*   colsB = (const int*)d_in[6];
    const float* valsB = (const float*)d_in[7];
    const int*   rows1 = (const int*)d_in[8];
    const int*   cols1 = (const int*)d_in[9];
    const float* vals1 = (const float*)d_in[10];
    const int*   rows2 = (const int*)d_in[11];
    const int*   cols2 = (const int*)d_in[12];
    const float* vals2 = (const float*)d_in[13];
    const float* G_d   = (const float*)d_in[14];
    const float* B_d   = (const float*)d_in[15];
    const float* Pd    = (const float*)d_in[16];
    const float* Qd    = (const float*)d_in[17];
    const float* W1    = (const float*)d_in[18];
    const float* b1    = (const float*)d_in[19];
    const float* W2    = (const float*)d_in[20];
    const float* b2    = (const float*)d_in[21];
    const float* w_ae  = (const float*)d_in[22];
    const float* b_ae  = (const float*)d_in[23];
    const float* w_af  = (const float*)d_in[24];
    const float* b_af  = (const float*)d_in[25];

    unsigned* arrs  = (unsigned*)d_ws;               // 8*NF uints (packed bf16 h|l)
    float* partials = (float*)(arrs + 8*NF);         // 128*11*8 = 11264
    float* att      = partials + 11264;              // 1024 (normalized weights)
    unsigned short* Wb1h = (unsigned short*)(att + 1024);  // 20480 shorts each
    unsigned short* Wb1l = Wb1h + 20480;
    unsigned short* Wb2h = Wb1l + 20480;
    unsigned short* Wb2l = Wb2h + 20480;
    int*   offs     = (int*)(Wb2l + 20480);          // 512*OSTR ints
    int2*  pairs    = (int2*)(offs + 512*OSTR);      // 512*PSTR int2 (padded CSR)
    unsigned* efh   = (unsigned*)(pairs + (size_t)512*PSTR);  // NF uints (bf16 e|f hi)
    unsigned* eflo  = efh + NF;                      // NF uints (bf16 e|f lo)

    csr_build<<<dim3(592 + NCOPY), dim3(256), 0, stream>>>(
        rowsG, colsG, valsG, rowsB, colsB, valsB,
        rows1, cols1, vals1, rows2, cols2, vals2,
        W1, W2, e, f, Wb1h, Wb1l, Wb2h, Wb2l, offs, pairs, efh, eflo);

    gather_all<<<dim3(2816), dim3(256), 0, stream>>>(
        e, f, efh, G_d, B_d, Pd, Qd, w_ae, w_af, offs, pairs, arrs, partials);

    attn_final<<<dim3(1), dim3(128), 0, stream>>>(partials, b_ae, b_af, att);

    final_fused<<<dim3(NTOT/16/FCH), dim3(256), 0, stream>>>(
        efh, eflo, arrs, att, Wb1h, Wb1l, Wb2h, Wb2l, b1, b2, (float*)d_out);
}

// Round 5
// 452.711 us; speedup vs baseline: 1.0300x; 1.0300x over previous
//
#include <hip/hip_runtime.h>
#include <math.h>

#define N_NODES 661
#define N_GRAPH 128
#define DEG 8
#define EPG (N_NODES*DEG)          // 5288 edges per graph per matrix
#define NTOT (N_NODES*N_GRAPH)     // 84608 nodes
#define FDIM 64
#define NF ((size_t)NTOT*FDIM)     // elements per [n,64] array
#define OSTR 672                   // padded CSR offsets stride
#define NTILE 11
#define TROWS 61                   // 11*61 = 671 >= 661
#define NCOPY 1056                 // ef-pack blocks appended to csr_build

using short8  = __attribute__((ext_vector_type(8))) short;
using float4v = __attribute__((ext_vector_type(4))) float;

__device__ __forceinline__ unsigned short f2bf(float x) {
    unsigned int u = __float_as_uint(x);
    unsigned int r = u + 0x7FFFu + ((u >> 16) & 1u);
    return (unsigned short)(r >> 16);
}
__device__ __forceinline__ float bf2f(unsigned short h) {
    return __uint_as_float(((unsigned int)h) << 16);
}
// pack float into (bf16_hi << 16) | bf16_lo residual
__device__ __forceinline__ unsigned pack_bf(float x) {
    unsigned short h = f2bf(x);
    unsigned short l = f2bf(x - bf2f(h));
    return ((unsigned)h << 16) | (unsigned)l;
}

// ---------------------------------------------------------------------------
// Kernel 1 (fused, round-1 proven): blocks 0..511 -> per-(graph,matrix) LDS
// counting sort -> CSR; blocks 512..591 -> wtrans (bf16 hi/lo W fragments in
// MFMA B-layout); blocks 592.. -> pack e/f into efh=(bf16e_hi<<16)|bf16f_hi
// AND eflo=(bf16e_lo<<16)|bf16f_lo.
// ---------------------------------------------------------------------------
__global__ __launch_bounds__(256) void csr_build(
    const int* __restrict__ rG, const int* __restrict__ cG, const float* __restrict__ vG,
    const int* __restrict__ rB, const int* __restrict__ cB, const float* __restrict__ vB,
    const int* __restrict__ r1, const int* __restrict__ c1, const float* __restrict__ v1,
    const int* __restrict__ r2, const int* __restrict__ c2, const float* __restrict__ v2,
    const float* __restrict__ W1, const float* __restrict__ W2,
    const float* __restrict__ e, const float* __restrict__ f,
    unsigned short* __restrict__ Wb1h, unsigned short* __restrict__ Wb1l,
    unsigned short* __restrict__ Wb2h, unsigned short* __restrict__ Wb2l,
    int* __restrict__ offs_out, int2* __restrict__ pairs_out,
    unsigned* __restrict__ efh, unsigned* __restrict__ eflo)
{
    int bid = blockIdx.x;
    int tid = threadIdx.x;

    if (bid >= 592) {                     // ---- ef bf16 hi/lo pair pack ----
        const int nf4 = (int)(NF/4);
        int i0 = (bid - 592)*256 + tid;
        const int stride = NCOPY*256;
        const float4v* e4 = (const float4v*)e;
        const float4v* f4 = (const float4v*)f;
        uint4* oh = (uint4*)efh;
        uint4* ol = (uint4*)eflo;
        for (int i = i0; i < nf4; i += stride) {
            float4v ev = e4[i];
            float4v fv = f4[i];
            uint4 uh, ul;
            unsigned short h, l;
            #define PK(idx, FLD) \
                h = f2bf(ev[idx]); l = f2bf(ev[idx] - bf2f(h)); \
                uh.FLD = ((unsigned)h << 16); ul.FLD = ((unsigned)l << 16); \
                h = f2bf(fv[idx]); l = f2bf(fv[idx] - bf2f(h)); \
                uh.FLD |= (unsigned)h; ul.FLD |= (unsigned)l;
            PK(0, x) PK(1, y) PK(2, z) PK(3, w)
            #undef PK
            oh[i] = uh;
            ol[i] = ul;
        }
        return;
    }

    if (bid >= 512) {                     // ---- wtrans part ----
        int i = (bid - 512)*256 + tid;    // 0..20479
        int j    = i & 7;
        int lane = (i >> 3) & 63;
        int ot   = (i >> 9) & 3;
        int ks   = i >> 11;
        int k = ks*32 + (lane >> 4)*8 + j;
        int o = ot*16 + (lane & 15);
        float w1 = W1[o*320 + k];
        float w2 = W2[o*320 + k];
        unsigned short h1 = f2bf(w1); Wb1h[i] = h1; Wb1l[i] = f2bf(w1 - bf2f(h1));
        unsigned short h2 = f2bf(w2); Wb2h[i] = h2; Wb2l[i] = f2bf(w2 - bf2f(h2));
        return;
    }

    __shared__ int   scount[N_NODES];
    __shared__ int   soffs[N_NODES+1];
    __shared__ int   scursor[N_NODES];
    __shared__ int   scol[EPG];
    __shared__ float sval[EPG];
    __shared__ int   sscan[256];

    int g = bid & 127;
    int m = bid >> 7;
    const int*   rows = (m==0)?rG:(m==1)?rB:(m==2)?r1:r2;
    const int*   cols = (m==0)?cG:(m==1)?cB:(m==2)?c1:c2;
    const float* vals = (m==0)?vG:(m==1)?vB:(m==2)?v1:v2;

    int ebase = g*EPG;
    int gbase = g*N_NODES;
    int seg = m*N_GRAPH + g;

    for (int i = tid; i < N_NODES; i += 256) scount[i] = 0;
    __syncthreads();
    for (int i = tid; i < EPG; i += 256)
        atomicAdd(&scount[rows[ebase+i] - gbase], 1);
    __syncthreads();

    int c0 = tid*3;
    int ps = 0;
    #pragma unroll
    for (int j = 0; j < 3; ++j) { int i = c0+j; if (i < N_NODES) ps += scount[i]; }
    sscan[tid] = ps;
    __syncthreads();
    #pragma unroll
    for (int d = 1; d < 256; d <<= 1) {
        int v = (tid >= d) ? sscan[tid-d] : 0;
        __syncthreads();
        sscan[tid] += v;
        __syncthreads();
    }
    int run = sscan[tid] - ps;   // exclusive prefix
    #pragma unroll
    for (int j = 0; j < 3; ++j) {
        int i = c0+j;
        if (i < N_NODES) { soffs[i] = run; scursor[i] = run; run += scount[i]; }
    }
    if (tid == 0) soffs[N_NODES] = EPG;
    __syncthreads();

    for (int i = tid; i < EPG; i += 256) {
        int r = rows[ebase+i] - gbase;
        int pos = atomicAdd(&scursor[r], 1);
        scol[pos] = cols[ebase+i];
        sval[pos] = vals[ebase+i];
    }
    __syncthreads();

    for (int i = tid; i <= N_NODES; i += 256)
        offs_out[(size_t)seg*OSTR + i] = soffs[i];
    int2* po = pairs_out + (size_t)seg*EPG;
    for (int i = tid; i < EPG; i += 256)
        po[i] = make_int2(scol[i], __float_as_int(sval[i]));
}

// ---------------------------------------------------------------------------
__device__ __forceinline__ void node_math1(
    float ev, float fv, float gd, float bd, float pd, float qd,
    float eGv, float fGv, float eBv, float fBv,
    float& e3v, float& nev, float& f3v, float& nfv)
{
    float invb = 1.0f/(ev*ev + fv*fv + 0.1f);
    float alpha = (pd*ev + qd*fv)*invb - eGv - fBv;
    float beta  = (qd*ev - pd*fv)*invb + fGv + eBv;
    float invg = 1.0f/(gd*gd + bd*bd);
    e3v = (alpha*gd + beta*bd)*invg;
    f3v = (beta*gd - alpha*bd)*invg;
    float bb1 = eGv - fBv, bb2 = fGv + eBv;
    float vv = ev*ev + fv*fv;
    float P_ = pd - vv*gd, Q_ = qd + vv*bd;
    nev = (P_*bb1 + Q_*bb2)*invg;
    nfv = (P_*bb2 - Q_*bb1)*invg;
}

// ---------------------------------------------------------------------------
// Kernel 2: gather SpMM (round-1 proven, 162 us). lane = feature; one packed
// bf16-pair dword gather per edge. A and B matrix batches interleaved.
// arrs: [0]=e3 [1]=ne [2]=e1 [3]=e2 [4]=f3 [5]=nf [6]=f1 [7]=f2
// Grid: 2816 = 8 XCD * 16 graphs * 22 (11 tiles x 2 sets).
// ---------------------------------------------------------------------------
__global__ __launch_bounds__(256) void gather_all(
    const float* __restrict__ e, const float* __restrict__ f,
    const unsigned* __restrict__ efh,
    const float* __restrict__ Gd, const float* __restrict__ Bd,
    const float* __restrict__ Pd, const float* __restrict__ Qd,
    const float* __restrict__ w_ae, const float* __restrict__ w_af,
    const int* __restrict__ offs, const int2* __restrict__ pairs,
    unsigned* __restrict__ arrs, float* __restrict__ partials)
{
    int tid = threadIdx.x, lane = tid & 63, wv = tid >> 6;
    int bid = blockIdx.x;
    int xcd = bid & 7, loc = bid >> 3;          // loc 0..351
    int g    = xcd*16 + loc/22;
    int sub  = loc % 22;
    int set  = (sub < NTILE) ? 0 : 1;
    int tile = sub - set*NTILE;
    int r0   = tile*TROWS;
    int rlim = min(TROWS, N_NODES - r0);
    int mA = set ? 2 : 0, mB = set ? 3 : 1;

    const int*  poA = offs + (size_t)(mA*N_GRAPH + g)*OSTR;
    const int*  poB = offs + (size_t)(mB*N_GRAPH + g)*OSTR;
    const int2* ppA = pairs + (size_t)(mA*N_GRAPH + g)*EPG;
    const int2* ppB = pairs + (size_t)(mB*N_GRAPH + g)*EPG;

    float wa = w_ae[lane], wf = w_af[lane];
    float pa0 = 0.f, pa1 = 0.f, pa2 = 0.f, pa3 = 0.f;

    for (int lr = wv; lr < rlim; lr += 4) {
        int r = r0 + lr;
        int node = g*N_NODES + r;
        int sA = __builtin_amdgcn_readfirstlane(poA[r]);
        int tA = __builtin_amdgcn_readfirstlane(poA[r+1]);
        int sB = __builtin_amdgcn_readfirstlane(poB[r]);
        int tB = __builtin_amdgcn_readfirstlane(poB[r+1]);
        int dA = tA - sA, dB = tB - sB;
        int nmax = max(dA, dB);

        float aE = 0.f, aF = 0.f, bE = 0.f, bF = 0.f;

        for (int base = 0; base < nmax; base += 8) {
            int2 pA[8], pB[8];
            #pragma unroll
            for (int j = 0; j < 8; ++j) {
                int k = base + j;
                int iA = (k < dA) ? (sA + k) : (sA ? sA - 1 : 0);
                int iB = (k < dB) ? (sB + k) : (sB ? sB - 1 : 0);
                pA[j] = ppA[iA];
                pB[j] = ppB[iB];
            }
            unsigned uA[8], uB[8];
            #pragma unroll
            for (int j = 0; j < 8; ++j) {
                unsigned oA = ((unsigned)pA[j].x << 6) + (unsigned)lane;
                unsigned oB = ((unsigned)pB[j].x << 6) + (unsigned)lane;
                uA[j] = efh[oA];
                uB[j] = efh[oB];
            }
            #pragma unroll
            for (int j = 0; j < 8; ++j) {
                int k = base + j;
                float vA = (k < dA) ? __int_as_float(pA[j].y) : 0.f;
                float vB = (k < dB) ? __int_as_float(pB[j].y) : 0.f;
                float evA = __uint_as_float(uA[j] & 0xFFFF0000u);
                float fvA = __uint_as_float(uA[j] << 16);
                float evB = __uint_as_float(uB[j] & 0xFFFF0000u);
                float fvB = __uint_as_float(uB[j] << 16);
                aE = fmaf(vA, evA, aE); aF = fmaf(vA, fvA, aF);
                bE = fmaf(vB, evB, bE); bF = fmaf(vB, fvB, bF);
            }
        }

        size_t idx = (size_t)node*FDIM + lane;
        if (set == 0) {
            float ev = e[idx], fv = f[idx];
            float gd = Gd[node], bd = Bd[node], pd = Pd[node], qd = Qd[node];
            float e3v, nev, f3v, nfv;
            node_math1(ev, fv, gd, bd, pd, qd, aE, aF, bE, bF, e3v, nev, f3v, nfv);
            arrs[0*NF + idx] = pack_bf(e3v);
            arrs[1*NF + idx] = pack_bf(nev);
            arrs[4*NF + idx] = pack_bf(f3v);
            arrs[5*NF + idx] = pack_bf(nfv);
            pa0 += e3v*wa; pa1 += nev*wa; pa2 += f3v*wf; pa3 += nfv*wf;
        } else {
            arrs[2*NF + idx] = pack_bf(aE);   // e1
            arrs[3*NF + idx] = pack_bf(bE);   // e2
            arrs[6*NF + idx] = pack_bf(aF);   // f1
            arrs[7*NF + idx] = pack_bf(bF);   // f2
            pa0 += aE*wa; pa1 += bE*wa; pa2 += aF*wf; pa3 += bF*wf;
        }
    }

    __shared__ float sred[4];
    if (tid < 4) sred[tid] = 0.f;
    __syncthreads();
    #pragma unroll
    for (int off = 32; off > 0; off >>= 1) {
        pa0 += __shfl_down(pa0, off); pa1 += __shfl_down(pa1, off);
        pa2 += __shfl_down(pa2, off); pa3 += __shfl_down(pa3, off);
    }
    if (lane == 0) {
        atomicAdd(&sred[0], pa0); atomicAdd(&sred[1], pa1);
        atomicAdd(&sred[2], pa2); atomicAdd(&sred[3], pa3);
    }
    __syncthreads();
    if (tid == 0) {
        float* pt = partials + ((size_t)g*NTILE + tile)*8;
        if (set == 0) { pt[0] = sred[0]; pt[1] = sred[1]; pt[4] = sred[2]; pt[5] = sred[3]; }
        else          { pt[2] = sred[0]; pt[3] = sred[1]; pt[6] = sred[2]; pt[7] = sred[3]; }
    }
}

// ---------------------------------------------------------------------------
// Kernel 3: finalize attention -> NORMALIZED weights att[g][0..3]=e, [4..7]=f
// ---------------------------------------------------------------------------
__global__ void attn_final(const float* __restrict__ partials,
                           const float* __restrict__ b_ae, const float* __restrict__ b_af,
                           float* __restrict__ att)
{
    int g = threadIdx.x;
    if (g >= N_GRAPH) return;
    float s[8];
    #pragma unroll
    for (int j = 0; j < 8; ++j) {
        float t = 0.f;
        for (int q = 0; q < NTILE; ++q) t += partials[((size_t)g*NTILE + q)*8 + j];
        s[j] = t;
    }
    float ae[4], af[4], se = 1e-4f, sf = 1e-4f;
    float bae = b_ae[0], baf = b_af[0];
    #pragma unroll
    for (int j = 0; j < 4; ++j) {
        float x = s[j]*(1.0f/N_NODES) + bae;
        ae[j] = 1.0f/(1.0f + expf(-x)); se += ae[j];
        float y = s[4+j]*(1.0f/N_NODES) + baf;
        af[j] = 1.0f/(1.0f + expf(-y)); sf += af[j];
    }
    #pragma unroll
    for (int j = 0; j < 4; ++j) {
        att[g*8 + j]     = ae[j]/se;
        att[g*8 + 4 + j] = af[j]/sf;
    }
}

// ---------------------------------------------------------------------------
// Helpers for final_fused fragment loads (direct, coalesced 16B loads).
// ---------------------------------------------------------------------------
__device__ __forceinline__ void frag_arrs(const unsigned* pe, const unsigned* pf,
        short8& ah, short8& al, short8& ch, short8& cl)
{
    uint4 ea = *(const uint4*)pe, eb = *(const uint4*)(pe + 4);
    uint4 fa = *(const uint4*)pf, fb = *(const uint4*)(pf + 4);
    unsigned ue[8] = {ea.x,ea.y,ea.z,ea.w,eb.x,eb.y,eb.z,eb.w};
    unsigned uf[8] = {fa.x,fa.y,fa.z,fa.w,fb.x,fb.y,fb.z,fb.w};
    #pragma unroll
    for (int j = 0; j < 8; ++j) {
        ah[j] = (short)(ue[j] >> 16);
        al[j] = (short)(ue[j] & 0xFFFFu);
        ch[j] = (short)(uf[j] >> 16);
        cl[j] = (short)(uf[j] & 0xFFFFu);
    }
}
__device__ __forceinline__ void frag_ef(const unsigned* ph, const unsigned* pl,
        short8& ah, short8& al, short8& ch, short8& cl)
{
    uint4 ha = *(const uint4*)ph, hb = *(const uint4*)(ph + 4);
    uint4 la = *(const uint4*)pl, lb = *(const uint4*)(pl + 4);
    unsigned uh[8] = {ha.x,ha.y,ha.z,ha.w,hb.x,hb.y,hb.z,hb.w};
    unsigned ul[8] = {la.x,la.y,la.z,la.w,lb.x,lb.y,lb.z,lb.w};
    #pragma unroll
    for (int j = 0; j < 8; ++j) {
        ah[j] = (short)(uh[j] >> 16);        // e hi
        al[j] = (short)(ul[j] >> 16);        // e lo
        ch[j] = (short)(uh[j] & 0xFFFFu);    // f hi
        cl[j] = (short)(ul[j] & 0xFFFFu);    // f lo
    }
}

// ---------------------------------------------------------------------------
// Kernel 4: MFMA epilogue v5 — direct-load (round-3 structure, 0 bank
// conflicts) but TWO 16-node chunks per block sharing each W load: W traffic
// halves (846->423 MB) and each W load feeds 12 MFMAs across 4 independent
// accumulator chains (e0/e1/f0/f1). No LDS. att read as uniform scalars.
// ---------------------------------------------------------------------------
__global__ __launch_bounds__(256, 2) void final_fused(
    const unsigned* __restrict__ efh, const unsigned* __restrict__ eflo,
    const unsigned* __restrict__ arrs,
    const float* __restrict__ att,
    const unsigned short* __restrict__ Wb1h, const unsigned short* __restrict__ Wb1l,
    const unsigned short* __restrict__ Wb2h, const unsigned short* __restrict__ Wb2l,
    const float* __restrict__ bv1, const float* __restrict__ bv2,
    float* __restrict__ out)
{
    int tid = threadIdx.x, lane = tid & 63, wv = tid >> 6;
    int m16 = lane & 15, quad = lane >> 4;
    int n0 = blockIdx.x * 32;                       // 2 chunks of 16 nodes
    size_t rb0 = (size_t)(n0 + m16)*FDIM + (unsigned)quad*8;
    size_t rb1 = rb0 + 16*FDIM;

    float4v acce0[5], accf0[5], acce1[5], accf1[5];
    #pragma unroll
    for (int s = 0; s < 5; ++s) {
        acce0[s] = (float4v){0.f,0.f,0.f,0.f};
        accf0[s] = (float4v){0.f,0.f,0.f,0.f};
        acce1[s] = (float4v){0.f,0.f,0.f,0.f};
        accf1[s] = (float4v){0.f,0.f,0.f,0.f};
    }

    #pragma unroll
    for (int seg = 0; seg < 5; ++seg) {
        #pragma unroll
        for (int ks2 = 0; ks2 < 2; ++ks2) {
            int ks = seg*2 + ks2;
            size_t boff = (size_t)((ks*4 + wv)*64 + lane)*8;
            short8 bh1 = *(const short8*)(Wb1h + boff);
            short8 bl1 = *(const short8*)(Wb1l + boff);
            short8 bh2 = *(const short8*)(Wb2h + boff);
            short8 bl2 = *(const short8*)(Wb2l + boff);

            short8 ah0, al0, ch0, cl0, ah1, al1, ch1, cl1;
            if (seg < 4) {
                const unsigned* pe = arrs + (size_t)seg*NF;
                const unsigned* pf = arrs + (size_t)(seg+4)*NF;
                frag_arrs(pe + rb0 + ks2*32, pf + rb0 + ks2*32, ah0, al0, ch0, cl0);
                frag_arrs(pe + rb1 + ks2*32, pf + rb1 + ks2*32, ah1, al1, ch1, cl1);
            } else {
                frag_ef(efh + rb0 + ks2*32, eflo + rb0 + ks2*32, ah0, al0, ch0, cl0);
                frag_ef(efh + rb1 + ks2*32, eflo + rb1 + ks2*32, ah1, al1, ch1, cl1);
            }

            // 4 independent chains interleaved (e0,e1,f0,f1) x (hh, lh, hl)
            acce0[seg] = __builtin_amdgcn_mfma_f32_16x16x32_bf16(ah0, bh1, acce0[seg], 0, 0, 0);
            acce1[seg] = __builtin_amdgcn_mfma_f32_16x16x32_bf16(ah1, bh1, acce1[seg], 0, 0, 0);
            accf0[seg] = __builtin_amdgcn_mfma_f32_16x16x32_bf16(ch0, bh2, accf0[seg], 0, 0, 0);
            accf1[seg] = __builtin_amdgcn_mfma_f32_16x16x32_bf16(ch1, bh2, accf1[seg], 0, 0, 0);
            acce0[seg] = __builtin_amdgcn_mfma_f32_16x16x32_bf16(al0, bh1, acce0[seg], 0, 0, 0);
            acce1[seg] = __builtin_amdgcn_mfma_f32_16x16x32_bf16(al1, bh1, acce1[seg], 0, 0, 0);
            accf0[seg] = __builtin_amdgcn_mfma_f32_16x16x32_bf16(cl0, bh2, accf0[seg], 0, 0, 0);
            accf1[seg] = __builtin_amdgcn_mfma_f32_16x16x32_bf16(cl1, bh2, accf1[seg], 0, 0, 0);
            acce0[seg] = __builtin_amdgcn_mfma_f32_16x16x32_bf16(ah0, bl1, acce0[seg], 0, 0, 0);
            acce1[seg] = __builtin_amdgcn_mfma_f32_16x16x32_bf16(ah1, bl1, acce1[seg], 0, 0, 0);
            accf0[seg] = __builtin_amdgcn_mfma_f32_16x16x32_bf16(ch0, bl2, accf0[seg], 0, 0, 0);
            accf1[seg] = __builtin_amdgcn_mfma_f32_16x16x32_bf16(ch1, bl2, accf1[seg], 0, 0, 0);
        }
    }

    int o = wv*16 + m16;
    float be = bv1[o], bf = bv2[o];

    #define EPILOG(CC, ACCE, ACCF)                                              \
    {                                                                           \
        int c = blockIdx.x*2 + (CC);                                            \
        int g0 = (c*16)/N_NODES;                                                \
        int nb = (g0+1)*N_NODES;                                                \
        int g1 = min(g0+1, N_GRAPH-1);                                          \
        float wE0[4], wF0[4], wE1[4], wF1[4];                                   \
        _Pragma("unroll")                                                       \
        for (int b = 0; b < 4; ++b) {                                           \
            wE0[b] = att[g0*8 + b];  wF0[b] = att[g0*8 + 4 + b];                \
            wE1[b] = att[g1*8 + b];  wF1[b] = att[g1*8 + 4 + b];                \
        }                                                                       \
        _Pragma("unroll")                                                       \
        for (int reg = 0; reg < 4; ++reg) {                                     \
            int node = c*16 + quad*4 + reg;                                     \
            bool hi = node >= nb;                                               \
            float se2 = ACCE[4][reg];                                           \
            float sf2 = ACCF[4][reg];                                           \
            _Pragma("unroll")                                                   \
            for (int b = 0; b < 4; ++b) {                                       \
                se2 = fmaf(hi ? wE1[b] : wE0[b], ACCE[b][reg], se2);            \
                sf2 = fmaf(hi ? wF1[b] : wF0[b], ACCF[b][reg], sf2);            \
            }                                                                   \
            out[(size_t)node*FDIM + o]      = tanhf(se2 + be);                  \
            out[NF + (size_t)node*FDIM + o] = tanhf(sf2 + bf);                  \
        }                                                                       \
    }

    EPILOG(0, acce0, accf0)
    EPILOG(1, acce1, accf1)
    #undef EPILOG
}

// ---------------------------------------------------------------------------
extern "C" void kernel_launch(void* const* d_in, const int* in_sizes, int n_in,
                              void* d_out, int out_size, void* d_ws, size_t ws_size,
                              hipStream_t stream) {
    (void)in_sizes; (void)n_in; (void)out_size; (void)ws_size;
    const float* e     = (const float*)d_in[0];
    const float* f     = (const float*)d_in[1];
    const int*   rowsG = (const int*)d_in[2];
    const int*   colsG = (const int*)d_in[3];
    const float* valsG = (const float*)d_in[4];
    const int*   rowsB = (const int*)d_in[5];
    const int*   colsB = (const int*)d_in[6];
    const float* valsB = (const float*)d_in[7];
    const int*   rows1 = (const int*)d_in[8];
    const int*   cols1 = (const int*)d_in[9];
    const float* vals1 = (const float*)d_in[10];
    const int*   rows2 = (const int*)d_in[11];
    const int*   cols2 = (const int*)d_in[12];
    const float* vals2 = (const float*)d_in[13];
    const float* G_d   = (const float*)d_in[14];
    const float* B_d   = (const float*)d_in[15];
    const float* Pd    = (const float*)d_in[16];
    const float* Qd    = (const float*)d_in[17];
    const float* W1    = (const float*)d_in[18];
    const float* b1    = (const float*)d_in[19];
    const float* W2    = (const float*)d_in[20];
    const float* b2    = (const float*)d_in[21];
    const float* w_ae  = (const float*)d_in[22];
    const float* b_ae  = (const float*)d_in[23];
    const float* w_af  = (const float*)d_in[24];
    const float* b_af  = (const float*)d_in[25];

    unsigned* arrs  = (unsigned*)d_ws;               // 8*NF uints (packed bf16 h|l)
    float* partials = (float*)(arrs + 8*NF);         // 128*11*8 = 11264
    float* att      = partials + 11264;              // 1024 (normalized weights)
    unsigned short* Wb1h = (unsigned short*)(att + 1024);  // 20480 shorts each
    unsigned short* Wb1l = Wb1h + 20480;
    unsigned short* Wb2h = Wb1l + 20480;
    unsigned short* Wb2l = Wb2h + 20480;
    int*   offs     = (int*)(Wb2l + 20480);          // 512*OSTR ints
    int2*  pairs    = (int2*)(offs + 512*OSTR);      // 512*EPG int2
    unsigned* efh   = (unsigned*)(pairs + (size_t)512*EPG);  // NF uints (bf16 e|f hi)
    unsigned* eflo  = efh + NF;                      // NF uints (bf16 e|f lo)

    csr_build<<<dim3(592 + NCOPY), dim3(256), 0, stream>>>(
        rowsG, colsG, valsG, rowsB, colsB, valsB,
        rows1, cols1, vals1, rows2, cols2, vals2,
        W1, W2, e, f, Wb1h, Wb1l, Wb2h, Wb2l, offs, pairs, efh, eflo);

    gather_all<<<dim3(2816), dim3(256), 0, stream>>>(
        e, f, efh, G_d, B_d, Pd, Qd, w_ae, w_af, offs, pairs, arrs, partials);

    attn_final<<<dim3(1), dim3(128), 0, stream>>>(partials, b_ae, b_af, att);

    final_fused<<<dim3(NTOT/32), dim3(256), 0, stream>>>(
        efh, eflo, arrs, att, Wb1h, Wb1l, Wb2h, Wb2l, b1, b2, (float*)d_out);
}

// Round 6
// 409.675 us; speedup vs baseline: 1.1381x; 1.1050x over previous
//
#include <hip/hip_runtime.h>
#include <math.h>

#define N_NODES 661
#define N_GRAPH 128
#define DEG 8
#define EPG (N_NODES*DEG)          // 5288 edges per graph per matrix
#define NTOT (N_NODES*N_GRAPH)     // 84608 nodes
#define FDIM 64
#define NF ((size_t)NTOT*FDIM)     // elements per [n,64] array
#define OSTR 672                   // padded CSR offsets stride
#define NTILE 11
#define TROWS 61                   // 11*61 = 671 >= 661
#define PACKB 1024                 // pack blocks in prep_pack

using short8  = __attribute__((ext_vector_type(8))) short;
using float4v = __attribute__((ext_vector_type(4))) float;

__device__ __forceinline__ unsigned short f2bf(float x) {
    unsigned int u = __float_as_uint(x);
    unsigned int r = u + 0x7FFFu + ((u >> 16) & 1u);
    return (unsigned short)(r >> 16);
}
__device__ __forceinline__ float bf2f(unsigned short h) {
    return __uint_as_float(((unsigned int)h) << 16);
}
// pack float into (bf16_hi << 16) | bf16_lo residual
__device__ __forceinline__ unsigned pack_bf(float x) {
    unsigned short h = f2bf(x);
    unsigned short l = f2bf(x - bf2f(h));
    return ((unsigned)h << 16) | (unsigned)l;
}

// ---------------------------------------------------------------------------
// Kernel 0: prep_pack — LDS-FREE streaming kernel (split out of csr_build so
// these blocks run at full occupancy instead of being throttled to 3/CU by
// the sorter's 51KB static LDS). blocks 0..79: wtrans (bf16 hi/lo W fragments
// in MFMA B-layout). blocks 80..: pack ef into (bf16(e)<<16)|bf16(f) words.
// ---------------------------------------------------------------------------
__global__ __launch_bounds__(256) void prep_pack(
    const float* __restrict__ W1, const float* __restrict__ W2,
    const float* __restrict__ e, const float* __restrict__ f,
    unsigned short* __restrict__ Wb1h, unsigned short* __restrict__ Wb1l,
    unsigned short* __restrict__ Wb2h, unsigned short* __restrict__ Wb2l,
    unsigned* __restrict__ efh)
{
    int bid = blockIdx.x;
    int tid = threadIdx.x;

    if (bid < 80) {                       // ---- wtrans part ----
        int i = bid*256 + tid;            // 0..20479
        int j    = i & 7;
        int lane = (i >> 3) & 63;
        int ot   = (i >> 9) & 3;
        int ks   = i >> 11;
        int k = ks*32 + (lane >> 4)*8 + j;
        int o = ot*16 + (lane & 15);
        float w1 = W1[o*320 + k];
        float w2 = W2[o*320 + k];
        unsigned short h1 = f2bf(w1); Wb1h[i] = h1; Wb1l[i] = f2bf(w1 - bf2f(h1));
        unsigned short h2 = f2bf(w2); Wb2h[i] = h2; Wb2l[i] = f2bf(w2 - bf2f(h2));
        return;
    }

    // ---- ef bf16-pair pack ----
    const int nf4 = (int)(NF/4);
    int i0 = (bid - 80)*256 + tid;
    const int stride = PACKB*256;
    const float4v* e4 = (const float4v*)e;
    const float4v* f4 = (const float4v*)f;
    uint4* o4 = (uint4*)efh;
    for (int i = i0; i < nf4; i += stride) {
        float4v ev = e4[i];
        float4v fv = f4[i];
        uint4 u;
        u.x = ((unsigned)f2bf(ev[0]) << 16) | (unsigned)f2bf(fv[0]);
        u.y = ((unsigned)f2bf(ev[1]) << 16) | (unsigned)f2bf(fv[1]);
        u.z = ((unsigned)f2bf(ev[2]) << 16) | (unsigned)f2bf(fv[2]);
        u.w = ((unsigned)f2bf(ev[3]) << 16) | (unsigned)f2bf(fv[3]);
        o4[i] = u;
    }
}

// ---------------------------------------------------------------------------
// Kernel 1: csr_build (round-1 proven sorter, now sort-ONLY, 512 blocks):
// per-(graph,matrix) LDS counting sort -> CSR.
// ---------------------------------------------------------------------------
__global__ __launch_bounds__(256) void csr_build(
    const int* __restrict__ rG, const int* __restrict__ cG, const float* __restrict__ vG,
    const int* __restrict__ rB, const int* __restrict__ cB, const float* __restrict__ vB,
    const int* __restrict__ r1, const int* __restrict__ c1, const float* __restrict__ v1,
    const int* __restrict__ r2, const int* __restrict__ c2, const float* __restrict__ v2,
    int* __restrict__ offs_out, int2* __restrict__ pairs_out)
{
    __shared__ int   scount[N_NODES];
    __shared__ int   soffs[N_NODES+1];
    __shared__ int   scursor[N_NODES];
    __shared__ int   scol[EPG];
    __shared__ float sval[EPG];
    __shared__ int   sscan[256];

    int bid = blockIdx.x;
    int tid = threadIdx.x;
    int g = bid & 127;
    int m = bid >> 7;
    const int*   rows = (m==0)?rG:(m==1)?rB:(m==2)?r1:r2;
    const int*   cols = (m==0)?cG:(m==1)?cB:(m==2)?c1:c2;
    const float* vals = (m==0)?vG:(m==1)?vB:(m==2)?v1:v2;

    int ebase = g*EPG;
    int gbase = g*N_NODES;
    int seg = m*N_GRAPH + g;

    for (int i = tid; i < N_NODES; i += 256) scount[i] = 0;
    __syncthreads();
    for (int i = tid; i < EPG; i += 256)
        atomicAdd(&scount[rows[ebase+i] - gbase], 1);
    __syncthreads();

    int c0 = tid*3;
    int ps = 0;
    #pragma unroll
    for (int j = 0; j < 3; ++j) { int i = c0+j; if (i < N_NODES) ps += scount[i]; }
    sscan[tid] = ps;
    __syncthreads();
    #pragma unroll
    for (int d = 1; d < 256; d <<= 1) {
        int v = (tid >= d) ? sscan[tid-d] : 0;
        __syncthreads();
        sscan[tid] += v;
        __syncthreads();
    }
    int run = sscan[tid] - ps;   // exclusive prefix
    #pragma unroll
    for (int j = 0; j < 3; ++j) {
        int i = c0+j;
        if (i < N_NODES) { soffs[i] = run; scursor[i] = run; run += scount[i]; }
    }
    if (tid == 0) soffs[N_NODES] = EPG;
    __syncthreads();

    for (int i = tid; i < EPG; i += 256) {
        int r = rows[ebase+i] - gbase;
        int pos = atomicAdd(&scursor[r], 1);
        scol[pos] = cols[ebase+i];
        sval[pos] = vals[ebase+i];
    }
    __syncthreads();

    for (int i = tid; i <= N_NODES; i += 256)
        offs_out[(size_t)seg*OSTR + i] = soffs[i];
    int2* po = pairs_out + (size_t)seg*EPG;
    for (int i = tid; i < EPG; i += 256)
        po[i] = make_int2(scol[i], __float_as_int(sval[i]));
}

// ---------------------------------------------------------------------------
__device__ __forceinline__ void node_math1(
    float ev, float fv, float gd, float bd, float pd, float qd,
    float eGv, float fGv, float eBv, float fBv,
    float& e3v, float& nev, float& f3v, float& nfv)
{
    float invb = 1.0f/(ev*ev + fv*fv + 0.1f);
    float alpha = (pd*ev + qd*fv)*invb - eGv - fBv;
    float beta  = (qd*ev - pd*fv)*invb + fGv + eBv;
    float invg = 1.0f/(gd*gd + bd*bd);
    e3v = (alpha*gd + beta*bd)*invg;
    f3v = (beta*gd - alpha*bd)*invg;
    float bb1 = eGv - fBv, bb2 = fGv + eBv;
    float vv = ev*ev + fv*fv;
    float P_ = pd - vv*gd, Q_ = qd + vv*bd;
    nev = (P_*bb1 + Q_*bb2)*invg;
    nfv = (P_*bb2 - Q_*bb1)*invg;
}

// ---------------------------------------------------------------------------
// Kernel 2: gather SpMM (round-1 proven, 162 us). lane = feature; one packed
// bf16-pair dword gather per edge. A and B matrix batches interleaved.
// arrs: [0]=e3 [1]=ne [2]=e1 [3]=e2 [4]=f3 [5]=nf [6]=f1 [7]=f2
// Grid: 2816 = 8 XCD * 16 graphs * 22 (11 tiles x 2 sets).
// ---------------------------------------------------------------------------
__global__ __launch_bounds__(256) void gather_all(
    const float* __restrict__ e, const float* __restrict__ f,
    const unsigned* __restrict__ efh,
    const float* __restrict__ Gd, const float* __restrict__ Bd,
    const float* __restrict__ Pd, const float* __restrict__ Qd,
    const float* __restrict__ w_ae, const float* __restrict__ w_af,
    const int* __restrict__ offs, const int2* __restrict__ pairs,
    unsigned* __restrict__ arrs, float* __restrict__ partials)
{
    int tid = threadIdx.x, lane = tid & 63, wv = tid >> 6;
    int bid = blockIdx.x;
    int xcd = bid & 7, loc = bid >> 3;          // loc 0..351
    int g    = xcd*16 + loc/22;
    int sub  = loc % 22;
    int set  = (sub < NTILE) ? 0 : 1;
    int tile = sub - set*NTILE;
    int r0   = tile*TROWS;
    int rlim = min(TROWS, N_NODES - r0);
    int mA = set ? 2 : 0, mB = set ? 3 : 1;

    const int*  poA = offs + (size_t)(mA*N_GRAPH + g)*OSTR;
    const int*  poB = offs + (size_t)(mB*N_GRAPH + g)*OSTR;
    const int2* ppA = pairs + (size_t)(mA*N_GRAPH + g)*EPG;
    const int2* ppB = pairs + (size_t)(mB*N_GRAPH + g)*EPG;

    float wa = w_ae[lane], wf = w_af[lane];
    float pa0 = 0.f, pa1 = 0.f, pa2 = 0.f, pa3 = 0.f;

    for (int lr = wv; lr < rlim; lr += 4) {
        int r = r0 + lr;
        int node = g*N_NODES + r;
        int sA = __builtin_amdgcn_readfirstlane(poA[r]);
        int tA = __builtin_amdgcn_readfirstlane(poA[r+1]);
        int sB = __builtin_amdgcn_readfirstlane(poB[r]);
        int tB = __builtin_amdgcn_readfirstlane(poB[r+1]);
        int dA = tA - sA, dB = tB - sB;
        int nmax = max(dA, dB);

        float aE = 0.f, aF = 0.f, bE = 0.f, bF = 0.f;

        for (int base = 0; base < nmax; base += 8) {
            int2 pA[8], pB[8];
            #pragma unroll
            for (int j = 0; j < 8; ++j) {
                int k = base + j;
                int iA = (k < dA) ? (sA + k) : (sA ? sA - 1 : 0);
                int iB = (k < dB) ? (sB + k) : (sB ? sB - 1 : 0);
                pA[j] = ppA[iA];
                pB[j] = ppB[iB];
            }
            unsigned uA[8], uB[8];
            #pragma unroll
            for (int j = 0; j < 8; ++j) {
                unsigned oA = ((unsigned)pA[j].x << 6) + (unsigned)lane;
                unsigned oB = ((unsigned)pB[j].x << 6) + (unsigned)lane;
                uA[j] = efh[oA];
                uB[j] = efh[oB];
            }
            #pragma unroll
            for (int j = 0; j < 8; ++j) {
                int k = base + j;
                float vA = (k < dA) ? __int_as_float(pA[j].y) : 0.f;
                float vB = (k < dB) ? __int_as_float(pB[j].y) : 0.f;
                float evA = __uint_as_float(uA[j] & 0xFFFF0000u);
                float fvA = __uint_as_float(uA[j] << 16);
                float evB = __uint_as_float(uB[j] & 0xFFFF0000u);
                float fvB = __uint_as_float(uB[j] << 16);
                aE = fmaf(vA, evA, aE); aF = fmaf(vA, fvA, aF);
                bE = fmaf(vB, evB, bE); bF = fmaf(vB, fvB, bF);
            }
        }

        size_t idx = (size_t)node*FDIM + lane;
        if (set == 0) {
            float ev = e[idx], fv = f[idx];
            float gd = Gd[node], bd = Bd[node], pd = Pd[node], qd = Qd[node];
            float e3v, nev, f3v, nfv;
            node_math1(ev, fv, gd, bd, pd, qd, aE, aF, bE, bF, e3v, nev, f3v, nfv);
            arrs[0*NF + idx] = pack_bf(e3v);
            arrs[1*NF + idx] = pack_bf(nev);
            arrs[4*NF + idx] = pack_bf(f3v);
            arrs[5*NF + idx] = pack_bf(nfv);
            pa0 += e3v*wa; pa1 += nev*wa; pa2 += f3v*wf; pa3 += nfv*wf;
        } else {
            arrs[2*NF + idx] = pack_bf(aE);   // e1
            arrs[3*NF + idx] = pack_bf(bE);   // e2
            arrs[6*NF + idx] = pack_bf(aF);   // f1
            arrs[7*NF + idx] = pack_bf(bF);   // f2
            pa0 += aE*wa; pa1 += bE*wa; pa2 += aF*wf; pa3 += bF*wf;
        }
    }

    __shared__ float sred[4];
    if (tid < 4) sred[tid] = 0.f;
    __syncthreads();
    #pragma unroll
    for (int off = 32; off > 0; off >>= 1) {
        pa0 += __shfl_down(pa0, off); pa1 += __shfl_down(pa1, off);
        pa2 += __shfl_down(pa2, off); pa3 += __shfl_down(pa3, off);
    }
    if (lane == 0) {
        atomicAdd(&sred[0], pa0); atomicAdd(&sred[1], pa1);
        atomicAdd(&sred[2], pa2); atomicAdd(&sred[3], pa3);
    }
    __syncthreads();
    if (tid == 0) {
        float* pt = partials + ((size_t)g*NTILE + tile)*8;
        if (set == 0) { pt[0] = sred[0]; pt[1] = sred[1]; pt[4] = sred[2]; pt[5] = sred[3]; }
        else          { pt[2] = sred[0]; pt[3] = sred[1]; pt[6] = sred[2]; pt[7] = sred[3]; }
    }
}

// ---------------------------------------------------------------------------
// Kernel 3: finalize attention weights (normalized)
// ---------------------------------------------------------------------------
__global__ void attn_final(const float* __restrict__ partials,
                           const float* __restrict__ b_ae, const float* __restrict__ b_af,
                           float* __restrict__ att)
{
    int g = threadIdx.x;
    if (g >= N_GRAPH) return;
    float s[8];
    #pragma unroll
    for (int j = 0; j < 8; ++j) {
        float t = 0.f;
        for (int q = 0; q < NTILE; ++q) t += partials[((size_t)g*NTILE + q)*8 + j];
        s[j] = t;
    }
    float ae[4], af[4], se = 1e-4f, sf = 1e-4f;
    float bae = b_ae[0], baf = b_af[0];
    #pragma unroll
    for (int j = 0; j < 4; ++j) {
        float x = s[j]*(1.0f/N_NODES) + bae;
        ae[j] = 1.0f/(1.0f + expf(-x)); se += ae[j];
        float y = s[4+j]*(1.0f/N_NODES) + baf;
        af[j] = 1.0f/(1.0f + expf(-y)); sf += af[j];
    }
    #pragma unroll
    for (int j = 0; j < 4; ++j) {
        att[g*8 + j]     = ae[j]/se;
        att[g*8 + 4 + j] = af[j]/sf;
    }
}

// ---------------------------------------------------------------------------
// Kernel 4: MFMA epilogue (round-1 proven). Stage packed-bf16 uints into LDS
// in fragment order (10 segs: e3,ne,e1,e2,e | f3,nf,f1,f2,f), unpack hi/lo
// with shifts, 5 per-segment accumulators, att folded post-MFMA, tanh+store.
// LDS slot layout: [seg*8 + (feat>>3)][node 0..15][8 elems], stride 132.
// ---------------------------------------------------------------------------
__global__ __launch_bounds__(256) void final_fused(
    const float* __restrict__ e, const float* __restrict__ f,
    const unsigned* __restrict__ arrs, const float* __restrict__ att,
    const unsigned short* __restrict__ Wb1h, const unsigned short* __restrict__ Wb1l,
    const unsigned short* __restrict__ Wb2h, const unsigned short* __restrict__ Wb2l,
    const float* __restrict__ bv1, const float* __restrict__ bv2,
    float* __restrict__ out)
{
    __shared__ __align__(16) unsigned sfrag[80*132];

    int tid = threadIdx.x, lane = tid & 63, chunk = tid >> 6;
    int node0 = blockIdx.x * 16;
    int sl = lane >> 3, jj = lane & 7;

    #pragma unroll
    for (int round = 0; round < 4; ++round) {
        int ni = round*4 + chunk;
        size_t idx = (size_t)(node0 + ni)*FDIM + lane;
        #pragma unroll
        for (int seg = 0; seg < 10; ++seg) {
            unsigned u;
            if (seg == 4)      u = pack_bf(e[idx]);
            else if (seg == 9) u = pack_bf(f[idx]);
            else {
                int a = (seg < 4) ? seg : seg - 1;   // segs 0..3 -> arrs0..3; 5..8 -> arrs4..7
                u = arrs[(size_t)a*NF + idx];
            }
            sfrag[(seg*8 + sl)*132 + ni*8 + jj] = u;
        }
    }
    __syncthreads();

    int m16 = lane & 15, quad = lane >> 4;
    float4v acce[5], accf[5];
    #pragma unroll
    for (int s = 0; s < 5; ++s) {
        acce[s] = (float4v){0.f,0.f,0.f,0.f};
        accf[s] = (float4v){0.f,0.f,0.f,0.f};
    }

    #pragma unroll
    for (int seg = 0; seg < 5; ++seg) {
        #pragma unroll
        for (int ks2 = 0; ks2 < 2; ++ks2) {
            int ks = seg*2 + ks2;
            size_t boff = (size_t)((ks*4 + chunk)*64 + lane)*8;
            // e-side
            {
                const unsigned* pa = &sfrag[(seg*8 + ks2*4 + quad)*132 + m16*8];
                uint4 ua = *(const uint4*)pa;
                uint4 ub = *(const uint4*)(pa + 4);
                unsigned uu[8] = {ua.x,ua.y,ua.z,ua.w,ub.x,ub.y,ub.z,ub.w};
                short8 ah, al;
                #pragma unroll
                for (int j = 0; j < 8; ++j) {
                    ah[j] = (short)(uu[j] >> 16);
                    al[j] = (short)(uu[j] & 0xFFFFu);
                }
                short8 bh = *(const short8*)(Wb1h + boff);
                short8 bl = *(const short8*)(Wb1l + boff);
                acce[seg] = __builtin_amdgcn_mfma_f32_16x16x32_bf16(ah, bh, acce[seg], 0, 0, 0);
                acce[seg] = __builtin_amdgcn_mfma_f32_16x16x32_bf16(al, bh, acce[seg], 0, 0, 0);
                acce[seg] = __builtin_amdgcn_mfma_f32_16x16x32_bf16(ah, bl, acce[seg], 0, 0, 0);
            }
            // f-side
            {
                const unsigned* pa = &sfrag[((seg+5)*8 + ks2*4 + quad)*132 + m16*8];
                uint4 ua = *(const uint4*)pa;
                uint4 ub = *(const uint4*)(pa + 4);
                unsigned uu[8] = {ua.x,ua.y,ua.z,ua.w,ub.x,ub.y,ub.z,ub.w};
                short8 ch, cl;
                #pragma unroll
                for (int j = 0; j < 8; ++j) {
                    ch[j] = (short)(uu[j] >> 16);
                    cl[j] = (short)(uu[j] & 0xFFFFu);
                }
                short8 bh = *(const short8*)(Wb2h + boff);
                short8 bl = *(const short8*)(Wb2l + boff);
                accf[seg] = __builtin_amdgcn_mfma_f32_16x16x32_bf16(ch, bh, accf[seg], 0, 0, 0);
                accf[seg] = __builtin_amdgcn_mfma_f32_16x16x32_bf16(cl, bh, accf[seg], 0, 0, 0);
                accf[seg] = __builtin_amdgcn_mfma_f32_16x16x32_bf16(ch, bl, accf[seg], 0, 0, 0);
            }
        }
    }

    int o = chunk*16 + m16;
    float be = bv1[o], bf = bv2[o];
    #pragma unroll
    for (int reg = 0; reg < 4; ++reg) {
        int node = node0 + quad*4 + reg;
        int g = node / N_NODES;
        float se2 = acce[4][reg];
        float sf2 = accf[4][reg];
        #pragma unroll
        for (int b = 0; b < 4; ++b) {
            se2 = fmaf(att[g*8 + b],     acce[b][reg], se2);
            sf2 = fmaf(att[g*8 + 4 + b], accf[b][reg], sf2);
        }
        out[(size_t)node*FDIM + o]      = tanhf(se2 + be);
        out[NF + (size_t)node*FDIM + o] = tanhf(sf2 + bf);
    }
}

// ---------------------------------------------------------------------------
extern "C" void kernel_launch(void* const* d_in, const int* in_sizes, int n_in,
                              void* d_out, int out_size, void* d_ws, size_t ws_size,
                              hipStream_t stream) {
    (void)in_sizes; (void)n_in; (void)out_size; (void)ws_size;
    const float* e     = (const float*)d_in[0];
    const float* f     = (const float*)d_in[1];
    const int*   rowsG = (const int*)d_in[2];
    const int*   colsG = (const int*)d_in[3];
    const float* valsG = (const float*)d_in[4];
    const int*   rowsB = (const int*)d_in[5];
    const int*   colsB = (const int*)d_in[6];
    const float* valsB = (const float*)d_in[7];
    const int*   rows1 = (const int*)d_in[8];
    const int*   cols1 = (const int*)d_in[9];
    const float* vals1 = (const float*)d_in[10];
    const int*   rows2 = (const int*)d_in[11];
    const int*   cols2 = (const int*)d_in[12];
    const float* vals2 = (const float*)d_in[13];
    const float* G_d   = (const float*)d_in[14];
    const float* B_d   = (const float*)d_in[15];
    const float* Pd    = (const float*)d_in[16];
    const float* Qd    = (const float*)d_in[17];
    const float* W1    = (const float*)d_in[18];
    const float* b1    = (const float*)d_in[19];
    const float* W2    = (const float*)d_in[20];
    const float* b2    = (const float*)d_in[21];
    const float* w_ae  = (const float*)d_in[22];
    const float* b_ae  = (const float*)d_in[23];
    const float* w_af  = (const float*)d_in[24];
    const float* b_af  = (const float*)d_in[25];

    unsigned* arrs  = (unsigned*)d_ws;               // 8*NF uints (packed bf16 h|l)
    float* partials = (float*)(arrs + 8*NF);         // 128*11*8 = 11264
    float* att      = partials + 11264;              // 1024 (normalized weights)
    unsigned short* Wb1h = (unsigned short*)(att + 1024);  // 20480 shorts each
    unsigned short* Wb1l = Wb1h + 20480;
    unsigned short* Wb2h = Wb1l + 20480;
    unsigned short* Wb2l = Wb2h + 20480;
    int*   offs     = (int*)(Wb2l + 20480);          // 512*OSTR ints
    int2*  pairs    = (int2*)(offs + 512*OSTR);      // 512*EPG int2
    unsigned* efh   = (unsigned*)(pairs + (size_t)512*EPG);  // NF uints (bf16 e|f pairs)

    prep_pack<<<dim3(80 + PACKB), dim3(256), 0, stream>>>(
        W1, W2, e, f, Wb1h, Wb1l, Wb2h, Wb2l, efh);

    csr_build<<<dim3(512), dim3(256), 0, stream>>>(
        rowsG, colsG, valsG, rowsB, colsB, valsB,
        rows1, cols1, vals1, rows2, cols2, vals2, offs, pairs);

    gather_all<<<dim3(2816), dim3(256), 0, stream>>>(
        e, f, efh, G_d, B_d, Pd, Qd, w_ae, w_af, offs, pairs, arrs, partials);

    attn_final<<<dim3(1), dim3(128), 0, stream>>>(partials, b_ae, b_af, att);

    final_fused<<<dim3(NTOT/16), dim3(256), 0, stream>>>(
        e, f, arrs, att, Wb1h, Wb1l, Wb2h, Wb2l, b1, b2, (float*)d_out);
}